// Round 20
// baseline (236.805 us; speedup 1.0000x reference)
//
#include <hip/hip_runtime.h>
#include <hip/hip_bf16.h>
#include <stdint.h>
#include <type_traits>

typedef __attribute__((ext_vector_type(8))) short short8;
typedef __attribute__((ext_vector_type(4))) float f32x4;
typedef __attribute__((ext_vector_type(16))) float f32x16;
typedef __attribute__((ext_vector_type(4))) unsigned int uint4v;
typedef __attribute__((ext_vector_type(2))) unsigned int uint2v;

#define DEV static __device__ __forceinline__

DEV short bf16b(float f) {
  return __builtin_bit_cast(short, __float2bfloat16(f));
}
DEV float exp2a(float x){ float r; asm("v_exp_f32 %0, %1" : "=v"(r) : "v"(x)); return r; }
DEV unsigned cvtpk(float lo, float hi){ unsigned r; asm("v_cvt_pk_bf16_f32 %0, %1, %2" : "=v"(r) : "v"(lo), "v"(hi)); return r; }
// permlane32_swap BUILTIN (R8-verified). swap(a,b) -> { [a.lo|b.lo], [a.hi|b.hi] }.
DEV uint2v plswap(unsigned a, unsigned b){
  return __builtin_amdgcn_permlane32_swap(a, b, false, false);
}

// ================= BM=64 GEMM geometry =================
// R19 showed the 128-tile GEMMs are latency-bound with ALL pipes idle
// (Mfma 14%, VALU 13%, HBM 18%) — more blocks/CU is the lever. BM=64
// doubles block count: grid (128,8[,z]) = 1024 blocks per z = 4 blocks/CU.
// 4 waves in 2x2; wave owns 32x64 (acc[2][4]). LDS 24KB (A 4KB + B 8KB, dbuf).

struct QKVArgs {
  const float *aq, *ak, *av;
  const float *wq, *wk, *wv;
  const float *bq, *bk, *bv;
  short *cq, *ck, *cv;
  float sq, sk, sv;
};

__global__ __launch_bounds__(256)
void qkv_gemm_kernel(QKVArgs a, int M, int N, int K)
{
  __shared__ __align__(16) short As[2][64*32];
  __shared__ __align__(16) short Bs[2][128*32];
  const int t = threadIdx.x;
  const int lane = t & 63;
  const int wv = t >> 6;
  const int wr = wv >> 1, wc = wv & 1;
  const int l15 = lane & 15, lg = lane >> 4;

  const int z = blockIdx.z;
  const float* A    = (z==0) ? a.aq : (z==1) ? a.ak : a.av;
  const float* W    = (z==0) ? a.wq : (z==1) ? a.wk : a.wv;
  const float* bias = (z==0) ? a.bq : (z==1) ? a.bk : a.bv;
  short* C          = (z==0) ? a.cq : (z==1) ? a.ck : a.cv;
  const float oscale= (z==0) ? a.sq : (z==1) ? a.sk : a.sv;

  const int id  = blockIdx.y * gridDim.x + blockIdx.x;
  const int nwg = gridDim.x * gridDim.y;          // 1024, divisible by 8
  const int wgid = (id & 7) * (nwg >> 3) + (id >> 3);
  const int bx = wgid >> 3;                        // 0..127
  const int by = wgid & 7;
  const int m0 = bx * 64;
  const int n0 = by * 128;

  // A staging: 1 chunk (64x32 = 2048 shorts / 256 thr = 8 each)
  const int arow = t >> 2, acol = (t & 3) * 8;
  const int abyte = arow*64 + ((acol*2) ^ ((arow&6)<<3));
  // B staging: 2 chunks (128x32 = 4096 shorts)
  int brow[2], bcol[2], bbyte[2];
  #pragma unroll
  for (int c=0;c<2;++c){
    const int e = t + c*256;
    brow[c] = e >> 2;
    bcol[c] = (e & 3) * 8;
    bbyte[c] = brow[c]*64 + ((bcol[c]*2) ^ ((brow[c]&6)<<3));
  }

  f32x4 acc[2][4] = {};

  // prologue: stage K-step 0
  {
    const float* src = A + (size_t)(m0+arow)*K + acol;
    f32x4 f0 = *(const f32x4*)src;
    f32x4 f1 = *(const f32x4*)(src+4);
    short8 va;
    #pragma unroll
    for (int j=0;j<4;++j){ va[j]=bf16b(f0[j]); va[4+j]=bf16b(f1[j]); }
    *(short8*)((char*)As[0] + abyte) = va;
    #pragma unroll
    for (int c=0;c<2;++c){
      const float* sB = W + (size_t)(n0+brow[c])*K + bcol[c];
      f32x4 g0 = *(const f32x4*)sB;
      f32x4 g1 = *(const f32x4*)(sB+4);
      short8 vb;
      #pragma unroll
      for (int j=0;j<4;++j){ vb[j]=bf16b(g0[j]); vb[4+j]=bf16b(g1[j]); }
      *(short8*)((char*)Bs[0] + bbyte[c]) = vb;
    }
  }
  __syncthreads();

  const int NK = K >> 5;
  for (int ks = 0; ks < NK; ++ks) {
    const int cur = ks & 1;
    const bool more = (ks + 1 < NK);

    f32x4 a0, a1, b0[2], b1[2];
    if (more) {
      const int k0 = (ks+1) << 5;
      const float* src = A + (size_t)(m0+arow)*K + k0 + acol;
      a0 = *(const f32x4*)src;
      a1 = *(const f32x4*)(src+4);
      #pragma unroll
      for (int c=0;c<2;++c){
        const float* sB = W + (size_t)(n0+brow[c])*K + k0 + bcol[c];
        b0[c] = *(const f32x4*)sB;
        b1[c] = *(const f32x4*)(sB+4);
      }
    }

    short8 af[2], bfr[4];
    #pragma unroll
    for (int m=0;m<2;++m) {
      const int row = wr*32 + m*16 + l15;
      af[m] = *(const short8*)((const char*)As[cur] + row*64 + ((lg*16) ^ ((row&6)<<3)));
    }
    #pragma unroll
    for (int n=0;n<4;++n) {
      const int row = wc*64 + n*16 + l15;
      bfr[n] = *(const short8*)((const char*)Bs[cur] + row*64 + ((lg*16) ^ ((row&6)<<3)));
    }
    #pragma unroll
    for (int m=0;m<2;++m)
      #pragma unroll
      for (int n=0;n<4;++n)
        acc[m][n] = __builtin_amdgcn_mfma_f32_16x16x32_bf16(af[m], bfr[n], acc[m][n], 0, 0, 0);

    if (more) {
      short8 va;
      #pragma unroll
      for (int j=0;j<4;++j){ va[j]=bf16b(a0[j]); va[4+j]=bf16b(a1[j]); }
      *(short8*)((char*)As[cur^1] + abyte) = va;
      #pragma unroll
      for (int c=0;c<2;++c){
        short8 vb;
        #pragma unroll
        for (int j=0;j<4;++j){ vb[j]=bf16b(b0[c][j]); vb[4+j]=bf16b(b1[c][j]); }
        *(short8*)((char*)Bs[cur^1] + bbyte[c]) = vb;
      }
    }
    __syncthreads();
  }

  #pragma unroll
  for (int n=0;n<4;++n) {
    const int col = n0 + wc*64 + n*16 + l15;
    const float bv = bias[col];
    #pragma unroll
    for (int m=0;m<2;++m) {
      #pragma unroll
      for (int i=0;i<4;++i) {
        const int row = m0 + wr*32 + m*16 + lg*4 + i;
        C[(size_t)row*N + col] = bf16b((acc[m][n][i] + bv) * oscale);
      }
    }
  }
}

// ---------------- out-projection GEMM (BM=64): C(fp32) = A(bf16) x W^T + bias ---
__global__ __launch_bounds__(256)
void gemm_out_kernel(const short* __restrict__ A, const float* __restrict__ W,
                     const float* __restrict__ bias, float* __restrict__ C,
                     int M, int N, int K)
{
  __shared__ __align__(16) short As[2][64*32];
  __shared__ __align__(16) short Bs[2][128*32];
  const int t = threadIdx.x;
  const int lane = t & 63;
  const int wv = t >> 6;
  const int wr = wv >> 1, wc = wv & 1;
  const int l15 = lane & 15, lg = lane >> 4;

  const int id  = blockIdx.y * gridDim.x + blockIdx.x;
  const int nwg = gridDim.x * gridDim.y;          // 1024
  const int wgid = (id & 7) * (nwg >> 3) + (id >> 3);
  const int bx = wgid >> 3;
  const int by = wgid & 7;
  const int m0 = bx * 64;
  const int n0 = by * 128;

  const int arow = t >> 2, acol = (t & 3) * 8;
  const int abyte = arow*64 + ((acol*2) ^ ((arow&6)<<3));
  int brow[2], bcol[2], bbyte[2];
  #pragma unroll
  for (int c=0;c<2;++c){
    const int e = t + c*256;
    brow[c] = e >> 2;
    bcol[c] = (e & 3) * 8;
    bbyte[c] = brow[c]*64 + ((bcol[c]*2) ^ ((brow[c]&6)<<3));
  }

  f32x4 acc[2][4] = {};

  {
    *(short8*)((char*)As[0] + abyte) = *(const short8*)(A + (size_t)(m0+arow)*K + acol);
    #pragma unroll
    for (int c=0;c<2;++c){
      const float* sB = W + (size_t)(n0+brow[c])*K + bcol[c];
      f32x4 g0 = *(const f32x4*)sB;
      f32x4 g1 = *(const f32x4*)(sB+4);
      short8 vb;
      #pragma unroll
      for (int j=0;j<4;++j){ vb[j]=bf16b(g0[j]); vb[4+j]=bf16b(g1[j]); }
      *(short8*)((char*)Bs[0] + bbyte[c]) = vb;
    }
  }
  __syncthreads();

  const int NK = K >> 5;
  for (int ks = 0; ks < NK; ++ks) {
    const int cur = ks & 1;
    const bool more = (ks + 1 < NK);

    short8 av;
    f32x4 b0[2], b1[2];
    if (more) {
      const int k0 = (ks+1) << 5;
      av = *(const short8*)(A + (size_t)(m0+arow)*K + k0 + acol);
      #pragma unroll
      for (int c=0;c<2;++c){
        const float* sB = W + (size_t)(n0+brow[c])*K + k0 + bcol[c];
        b0[c] = *(const f32x4*)sB;
        b1[c] = *(const f32x4*)(sB+4);
      }
    }

    short8 af[2], bfr[4];
    #pragma unroll
    for (int m=0;m<2;++m) {
      const int row = wr*32 + m*16 + l15;
      af[m] = *(const short8*)((const char*)As[cur] + row*64 + ((lg*16) ^ ((row&6)<<3)));
    }
    #pragma unroll
    for (int n=0;n<4;++n) {
      const int row = wc*64 + n*16 + l15;
      bfr[n] = *(const short8*)((const char*)Bs[cur] + row*64 + ((lg*16) ^ ((row&6)<<3)));
    }
    #pragma unroll
    for (int m=0;m<2;++m)
      #pragma unroll
      for (int n=0;n<4;++n)
        acc[m][n] = __builtin_amdgcn_mfma_f32_16x16x32_bf16(af[m], bfr[n], acc[m][n], 0, 0, 0);

    if (more) {
      *(short8*)((char*)As[cur^1] + abyte) = av;
      #pragma unroll
      for (int c=0;c<2;++c){
        short8 vb;
        #pragma unroll
        for (int j=0;j<4;++j){ vb[j]=bf16b(b0[c][j]); vb[4+j]=bf16b(b1[c][j]); }
        *(short8*)((char*)Bs[cur^1] + bbyte[c]) = vb;
      }
    }
    __syncthreads();
  }

  #pragma unroll
  for (int n=0;n<4;++n) {
    const int col = n0 + wc*64 + n*16 + l15;
    const float bv = bias[col];
    #pragma unroll
    for (int m=0;m<2;++m) {
      #pragma unroll
      for (int i=0;i<4;++i) {
        const int row = m0 + wr*32 + m*16 + lg*4 + i;
        C[(size_t)row*N + col] = acc[m][n][i] + bv;
      }
    }
  }
}

// ---------------- mask scan: per batch, ordered indices of unmasked keys ----
__global__ __launch_bounds__(256)
void scan_kernel(const int* __restrict__ mask, int* __restrict__ IDX, int* __restrict__ cnt)
{
  const int b = blockIdx.x;
  const int t = threadIdx.x;
  const int* m = mask + (size_t)b*4096;
  __shared__ int psum[256];
  int loc[16]; int c = 0;
  const int base = t*16;
  #pragma unroll
  for (int j=0;j<16;++j){ loc[j] = (m[base+j] != 0) ? 1 : 0; c += loc[j]; }
  psum[t] = c;
  __syncthreads();
  for (int off=1; off<256; off<<=1){
    int add = (t >= off) ? psum[t-off] : 0;
    __syncthreads();
    psum[t] += add;
    __syncthreads();
  }
  int j2 = psum[t] - c;
  #pragma unroll
  for (int j=0;j<16;++j)
    if (loc[j]) IDX[(size_t)b*4096 + (j2++)] = base + j;
  if (t == 255) cnt[b] = psum[255];
}

// ---------------- K gather: compact K rows (contiguous KC), pads zeroed -------
__global__ __launch_bounds__(256)
void kgather_kernel(const short* __restrict__ KH, const int* __restrict__ IDX,
                    const int* __restrict__ cnt, short* __restrict__ KC)
{
  const int b = blockIdx.y;
  const int c = cnt[b];
  const int rc = (c + 63) & ~63;
  const int g = threadIdx.x >> 4;
  const int l = threadIdx.x & 15;
  const int j = blockIdx.x*16 + g;
  if (j >= rc) return;
  const size_t dst = ((size_t)b*4096 + j)*1024;
  if (j < c) {
    const int i = IDX[(size_t)b*4096 + j];
    const size_t src = ((size_t)b*4096 + i)*1024;
    #pragma unroll
    for (int ch=0; ch<8; ++ch)
      *(short8*)(KC + dst + ch*128 + l*8) = *(const short8*)(KH + src + ch*128 + l*8);
  } else {
    short8 z = {};
    #pragma unroll
    for (int ch=0; ch<8; ++ch)
      *(short8*)(KC + dst + ch*128 + l*8) = z;
  }
}

// ---------------- V transpose (gathering): VH rows IDX[j] -> Vt[(bh)*64+dk][j] ----
__global__ __launch_bounds__(256)
void transpose_v_kernel(const short* __restrict__ Vh, short* __restrict__ Vt,
                        const int* __restrict__ IDX, const int* __restrict__ cnt)
{
  __shared__ short tile[64][65];
  const int t = threadIdx.x;
  const int bh = blockIdx.y, b = bh >> 4, h = bh & 15;
  const int s0 = blockIdx.x * 64;
  const int c = cnt[b];
  if (s0 >= ((c + 63) & ~63)) return;
  const int r = t >> 2;
  const int cc = (t & 3) * 16;
  short8 v0 = {}, v1 = {};
  if (s0 + r < c) {
    const int srcRow = IDX[(size_t)b*4096 + s0 + r];
    const short* src = Vh + (size_t)(b*4096 + srcRow)*1024 + h*64 + cc;
    v0 = *(const short8*)src;
    v1 = *(const short8*)(src + 8);
  }
  #pragma unroll
  for (int j=0;j<8;++j){ tile[r][cc+j]=v0[j]; tile[r][cc+8+j]=v1[j]; }
  __syncthreads();
  short8 o0, o1;
  #pragma unroll
  for (int j=0;j<8;++j){ o0[j]=tile[cc+j][r]; o1[j]=tile[cc+8+j][r]; }
  short* dst = Vt + (size_t)(bh*64 + r)*4096 + s0 + cc;
  *(short8*)dst = o0;
  *(short8*)(dst+8) = o1;
}

// ---------------- Flash attention over compacted keys (contiguous KC) ---------
__global__ __launch_bounds__(256, 2)
void flash_kernel(const short* __restrict__ Qh, const short* __restrict__ Kh,
                  const short* __restrict__ Vt,
                  const int* __restrict__ cnt, short* __restrict__ O)
{
  __shared__ __align__(16) char smem[32768];
  char* KsBufB = smem;
  char* VsBufB = smem + 16384;

  const int t = threadIdx.x;
  const int lane = t & 63, wv = t >> 6;
  const int l31 = lane & 31, hi = lane >> 5;
  const int rsw = (l31 & 7) << 4;
  const int bh = blockIdx.y, b = bh >> 4, h = bh & 15;
  const int q0 = blockIdx.x * 256;
  const bool lo = (lane < 32);

  const int cB = cnt[b];
  const int NT = (cB + 63) >> 6;

  short8 qf[2][4];
  #pragma unroll
  for (int qh=0; qh<2; ++qh) {
    const short* qrow = Qh + (size_t)(b*4096 + q0 + wv*64 + qh*32 + l31)*1024 + h*64;
    #pragma unroll
    for (int ds=0; ds<4; ++ds)
      qf[qh][ds] = *(const short8*)(qrow + ds*16 + hi*8);
  }

  float l_run[2] = {0.0f, 0.0f};
  f32x16 oA[2][2] = {};

  #pragma unroll
  for (int c = 0; c < 2; ++c) {
    const int e = t + c*256;
    const int row = e >> 3, sl = e & 7;
    const int byte = row*128 + ((sl*16) ^ ((row&7)<<4));
    *(short8*)(KsBufB + byte) =
      *(const short8*)(Kh + (size_t)(b*4096 + row)*1024 + h*64 + sl*8);
    *(short8*)(VsBufB + byte) =
      *(const short8*)(Vt + (size_t)(bh*64 + row)*4096 + sl*8);
  }
  __syncthreads();

  for (int kt = 0; kt < NT; ++kt) {
    const int cur = kt & 1;
    const char* KsC = KsBufB + cur*8192;
    const char* VsC = VsBufB + cur*8192;
    const bool more = (kt + 1 < NT);

    f32x16 sA[2][2];
    if (more) {
      #pragma unroll
      for (int qh=0;qh<2;++qh)
        #pragma unroll
        for (int kh=0;kh<2;++kh)
          sA[qh][kh] = (f32x16){};
    } else {
      const int kbase = kt*64 - cB;
      #pragma unroll
      for (int kh=0;kh<2;++kh)
        #pragma unroll
        for (int r=0;r<16;++r) {
          const int key = kh*32 + (r>>2)*8 + hi*4 + (r&3);
          const float mv = (kbase + key < 0) ? 0.0f : -1.0e9f;
          sA[0][kh][r] = mv;
          sA[1][kh][r] = mv;
        }
    }

    __builtin_amdgcn_s_setprio(1);
    #pragma unroll
    for (int ds=0; ds<4; ++ds) {
      short8 kf0 = *(const short8*)(KsC + l31*128       + ((ds*32 + hi*16) ^ rsw));
      short8 kf1 = *(const short8*)(KsC + (l31+32)*128  + ((ds*32 + hi*16) ^ rsw));
      sA[0][0] = __builtin_amdgcn_mfma_f32_32x32x16_bf16(kf0, qf[0][ds], sA[0][0], 0,0,0);
      sA[0][1] = __builtin_amdgcn_mfma_f32_32x32x16_bf16(kf1, qf[0][ds], sA[0][1], 0,0,0);
      sA[1][0] = __builtin_amdgcn_mfma_f32_32x32x16_bf16(kf0, qf[1][ds], sA[1][0], 0,0,0);
      sA[1][1] = __builtin_amdgcn_mfma_f32_32x32x16_bf16(kf1, qf[1][ds], sA[1][1], 0,0,0);
    }
    __builtin_amdgcn_s_setprio(0);

    short8 nk[2], nv[2];
    if (more) {
      #pragma unroll
      for (int c=0;c<2;++c){
        const int e = t + c*256; const int row = e>>3, sl = e&7;
        nk[c] = *(const short8*)(Kh + (size_t)(b*4096 + (kt+1)*64 + row)*1024 + h*64 + sl*8);
        nv[c] = *(const short8*)(Vt + (size_t)(bh*64 + row)*4096 + (kt+1)*64 + sl*8);
      }
    }

    #pragma unroll
    for (int qh=0; qh<2; ++qh) {
      f32x4 lp = {0.f,0.f,0.f,0.f};
      #pragma unroll
      for (int kh=0;kh<2;++kh)
        #pragma unroll
        for (int r=0;r<16;++r) {
          const float p = exp2a(sA[qh][kh][r]);
          sA[qh][kh][r] = p;
          lp[r&3] += p;
        }
      l_run[qh] += (lp[0]+lp[1]) + (lp[2]+lp[3]);
    }

    __builtin_amdgcn_s_setprio(1);
    #pragma unroll
    for (int tt=0;tt<4;++tt) {
      const int kh = tt>>1, ro = (tt&1)*8;
      unsigned w0[4], w1[4];
      {
        unsigned c01 = cvtpk(sA[0][kh][ro+0], sA[0][kh][ro+1]);
        unsigned c23 = cvtpk(sA[0][kh][ro+2], sA[0][kh][ro+3]);
        unsigned c45 = cvtpk(sA[0][kh][ro+4], sA[0][kh][ro+5]);
        unsigned c67 = cvtpk(sA[0][kh][ro+6], sA[0][kh][ro+7]);
        uint2v r02 = plswap(c01, c45);
        uint2v r13 = plswap(c23, c67);
        w0[0]=r02[0]; w0[1]=r13[0]; w0[2]=r02[1]; w0[3]=r13[1];
      }
      {
        unsigned c01 = cvtpk(sA[1][kh][ro+0], sA[1][kh][ro+1]);
        unsigned c23 = cvtpk(sA[1][kh][ro+2], sA[1][kh][ro+3]);
        unsigned c45 = cvtpk(sA[1][kh][ro+4], sA[1][kh][ro+5]);
        unsigned c67 = cvtpk(sA[1][kh][ro+6], sA[1][kh][ro+7]);
        uint2v r02 = plswap(c01, c45);
        uint2v r13 = plswap(c23, c67);
        w1[0]=r02[0]; w1[1]=r13[0]; w1[2]=r02[1]; w1[3]=r13[1];
      }
      #pragma unroll
      for (int n=0;n<2;++n) {
        short8 vf = *(const short8*)(VsC + (n*32+l31)*128 + ((tt*32 + hi*16) ^ rsw));
        uint4v wp0 = {w0[0], w0[1], w0[2], w0[3]};
        uint4v wp1 = {w1[0], w1[1], w1[2], w1[3]};
        oA[0][n] = __builtin_amdgcn_mfma_f32_32x32x16_bf16(vf, __builtin_bit_cast(short8, wp0), oA[0][n], 0,0,0);
        oA[1][n] = __builtin_amdgcn_mfma_f32_32x32x16_bf16(vf, __builtin_bit_cast(short8, wp1), oA[1][n], 0,0,0);
      }
    }
    __builtin_amdgcn_s_setprio(0);

    if (more) {
      #pragma unroll
      for (int c=0;c<2;++c){
        const int e = t + c*256; const int row = e>>3, sl = e&7;
        const int byte = row*128 + ((sl*16) ^ ((row&7)<<4));
        *(short8*)(KsBufB + (cur^1)*8192 + byte) = nk[c];
        *(short8*)(VsBufB + (cur^1)*8192 + byte) = nv[c];
      }
    }
    __syncthreads();
  }

  char* ot = smem + wv*4096;
  #pragma unroll
  for (int qh=0; qh<2; ++qh) {
    float lr = l_run[qh];
    {
      uint2v rl = plswap(__builtin_bit_cast(unsigned, lr), __builtin_bit_cast(unsigned, lr));
      lr += __builtin_bit_cast(float, lo ? rl[1] : rl[0]);
    }
    const float inv = 1.0f / lr;
    #pragma unroll
    for (int n=0;n<2;++n)
      #pragma unroll
      for (int rq=0;rq<4;++rq) {
        const unsigned w0 = cvtpk(oA[qh][n][rq*4+0]*inv, oA[qh][n][rq*4+1]*inv);
        const unsigned w1 = cvtpk(oA[qh][n][rq*4+2]*inv, oA[qh][n][rq*4+3]*inv);
        const int sl = n*4 + rq;
        const int byte = l31*128 + ((sl*16) ^ ((l31&7)<<4)) + hi*8;
        *(unsigned*)(ot + byte)     = w0;
        *(unsigned*)(ot + byte + 4) = w1;
      }
    asm volatile("s_waitcnt lgkmcnt(0)" ::: "memory");
    __builtin_amdgcn_sched_barrier(0);

    const int row = lane >> 1, half = lane & 1;
    const int orow = b*4096 + q0 + wv*64 + qh*32 + row;
    #pragma unroll
    for (int i=0;i<4;++i) {
      const int sl = half*4 + i;
      short8 vv = *(const short8*)(ot + row*128 + ((sl*16) ^ ((row&7)<<4)));
      *(short8*)(O + (size_t)orow*1024 + h*64 + half*32 + i*8) = vv;
    }
    asm volatile("s_waitcnt lgkmcnt(0)" ::: "memory");
    __builtin_amdgcn_sched_barrier(0);
  }
}

extern "C" void kernel_launch(void* const* d_in, const int* in_sizes, int n_in,
                              void* d_out, int out_size, void* d_ws, size_t ws_size,
                              hipStream_t stream)
{
  const float* q    = (const float*)d_in[0];
  const float* k    = (const float*)d_in[1];
  const float* v    = (const float*)d_in[2];
  const int*   mask = (const int*)d_in[3];
  const float* w_q  = (const float*)d_in[4];
  const float* b_q  = (const float*)d_in[5];
  const float* w_k  = (const float*)d_in[6];
  const float* b_k  = (const float*)d_in[7];
  const float* w_v  = (const float*)d_in[8];
  const float* b_v  = (const float*)d_in[9];
  const float* w_o  = (const float*)d_in[10];
  const float* b_o  = (const float*)d_in[11];
  float* out = (float*)d_out;

  char* ws = (char*)d_ws;
  const size_t SZ = (size_t)8192*1024*2;   // one bf16 [8192][1024] buffer = 16MB
  short* QH = (short*)(ws);
  short* KH = (short*)(ws + SZ);
  short* OB = (short*)(ws + 2*SZ);         // V-proj output, then reused for attn out
  short* VT = (short*)(ws + 3*SZ);
  short* KC = (short*)(ws + 4*SZ);         // compacted K (ws >= 96MB proven in R16)
  int*   IDX = (int*)(ws + 5*SZ);          // 32KB
  int*   CNT = (int*)(ws + 5*SZ + 32768);  // 8B
  short* VH = OB;

  const float QSCALE = 0.125f * 1.44269504f;

  QKVArgs qa;
  qa.aq = q;   qa.ak = k;   qa.av = v;
  qa.wq = w_q; qa.wk = w_k; qa.wv = w_v;
  qa.bq = b_q; qa.bk = b_k; qa.bv = b_v;
  qa.cq = QH;  qa.ck = KH;  qa.cv = VH;
  qa.sq = QSCALE; qa.sk = 1.0f; qa.sv = 1.0f;

  dim3 bG(256);
  hipLaunchKernelGGL(qkv_gemm_kernel, dim3(128, 8, 3), bG, 0, stream, qa, 8192, 1024, 1024);
  hipLaunchKernelGGL(scan_kernel, dim3(2), bG, 0, stream, mask, IDX, CNT);
  hipLaunchKernelGGL(kgather_kernel, dim3(256, 2), bG, 0, stream, KH, IDX, CNT, KC);
  hipLaunchKernelGGL(transpose_v_kernel, dim3(64, 32), bG, 0, stream, VH, VT, IDX, CNT);
  hipLaunchKernelGGL(flash_kernel, dim3(16, 32), bG, 0, stream, QH, KC, VT, CNT, OB);
  hipLaunchKernelGGL(gemm_out_kernel, dim3(128, 8), bG, 0, stream, OB, w_o, b_o, out, 8192, 1024, 1024);
}

// Round 21
// 204.750 us; speedup vs baseline: 1.1566x; 1.1566x over previous
//
#include <hip/hip_runtime.h>
#include <hip/hip_bf16.h>
#include <stdint.h>
#include <type_traits>

typedef __attribute__((ext_vector_type(8))) short short8;
typedef __attribute__((ext_vector_type(4))) float f32x4;
typedef __attribute__((ext_vector_type(16))) float f32x16;
typedef __attribute__((ext_vector_type(4))) unsigned int uint4v;
typedef __attribute__((ext_vector_type(2))) unsigned int uint2v;

#define DEV static __device__ __forceinline__

DEV short bf16b(float f) {
  return __builtin_bit_cast(short, __float2bfloat16(f));
}
DEV float exp2a(float x){ float r; asm("v_exp_f32 %0, %1" : "=v"(r) : "v"(x)); return r; }
DEV unsigned cvtpk(float lo, float hi){ unsigned r; asm("v_cvt_pk_bf16_f32 %0, %1, %2" : "=v"(r) : "v"(lo), "v"(hi)); return r; }
// permlane32_swap BUILTIN (R8-verified). swap(a,b) -> { [a.lo|b.lo], [a.hi|b.hi] }.
DEV uint2v plswap(unsigned a, unsigned b){
  return __builtin_amdgcn_permlane32_swap(a, b, false, false);
}

// ================= fused QKV projection GEMM (BM=128, R19-verified) =============
// gridDim.z=3 selects {A, W, bias, C, oscale} per projection.
// BM=64 (R20) regressed: more blocks didn't lift MfmaUtil but raised FETCH 14%.
struct QKVArgs {
  const float *aq, *ak, *av;
  const float *wq, *wk, *wv;
  const float *bq, *bk, *bv;
  short *cq, *ck, *cv;
  float sq, sk, sv;
};

__global__ __launch_bounds__(256)
void qkv_gemm_kernel(QKVArgs a, int M, int N, int K)
{
  __shared__ __align__(16) short As[2][128*32];
  __shared__ __align__(16) short Bs[2][128*32];
  const int t = threadIdx.x;
  const int lane = t & 63;
  const int wv = t >> 6;
  const int wr = wv >> 1, wc = wv & 1;
  const int l15 = lane & 15, lg = lane >> 4;

  const int z = blockIdx.z;
  const float* A    = (z==0) ? a.aq : (z==1) ? a.ak : a.av;
  const float* W    = (z==0) ? a.wq : (z==1) ? a.wk : a.wv;
  const float* bias = (z==0) ? a.bq : (z==1) ? a.bk : a.bv;
  short* C          = (z==0) ? a.cq : (z==1) ? a.ck : a.cv;
  const float oscale= (z==0) ? a.sq : (z==1) ? a.sk : a.sv;

  const int id  = blockIdx.y * gridDim.x + blockIdx.x;
  const int nwg = gridDim.x * gridDim.y;          // 512, divisible by 8
  const int wgid = (id & 7) * (nwg >> 3) + (id >> 3);
  const int bx = wgid >> 3;                        // gridDim.y == 8
  const int by = wgid & 7;
  const int m0 = bx * 128;
  const int n0 = by * 128;

  int srow[2], scol[2], sbyte[2];
  #pragma unroll
  for (int c=0;c<2;++c){
    const int e = t + c*256;
    srow[c] = e >> 2;
    scol[c] = (e & 3) * 8;
    sbyte[c] = srow[c]*64 + ((scol[c]*2) ^ ((srow[c]&6)<<3));
  }

  f32x4 acc[4][4] = {};

  #pragma unroll
  for (int c=0;c<2;++c){
    const float* src = A + (size_t)(m0+srow[c])*K + scol[c];
    f32x4 f0 = *(const f32x4*)src;
    f32x4 f1 = *(const f32x4*)(src+4);
    short8 va;
    #pragma unroll
    for (int j=0;j<4;++j){ va[j]=bf16b(f0[j]); va[4+j]=bf16b(f1[j]); }
    *(short8*)((char*)As[0] + sbyte[c]) = va;
    const float* sB = W + (size_t)(n0+srow[c])*K + scol[c];
    f32x4 g0 = *(const f32x4*)sB;
    f32x4 g1 = *(const f32x4*)(sB+4);
    short8 vb;
    #pragma unroll
    for (int j=0;j<4;++j){ vb[j]=bf16b(g0[j]); vb[4+j]=bf16b(g1[j]); }
    *(short8*)((char*)Bs[0] + sbyte[c]) = vb;
  }
  __syncthreads();

  const int NK = K >> 5;
  for (int ks = 0; ks < NK; ++ks) {
    const int cur = ks & 1;
    const bool more = (ks + 1 < NK);

    f32x4 a0[2], a1[2], b0[2], b1[2];
    if (more) {
      const int k0 = (ks+1) << 5;
      #pragma unroll
      for (int c=0;c<2;++c){
        const float* src = A + (size_t)(m0+srow[c])*K + k0 + scol[c];
        a0[c] = *(const f32x4*)src;
        a1[c] = *(const f32x4*)(src+4);
        const float* sB = W + (size_t)(n0+srow[c])*K + k0 + scol[c];
        b0[c] = *(const f32x4*)sB;
        b1[c] = *(const f32x4*)(sB+4);
      }
    }

    short8 af[4], bfr[4];
    #pragma unroll
    for (int m=0;m<4;++m) {
      const int row = wr*64 + m*16 + l15;
      af[m] = *(const short8*)((const char*)As[cur] + row*64 + ((lg*16) ^ ((row&6)<<3)));
    }
    #pragma unroll
    for (int n=0;n<4;++n) {
      const int row = wc*64 + n*16 + l15;
      bfr[n] = *(const short8*)((const char*)Bs[cur] + row*64 + ((lg*16) ^ ((row&6)<<3)));
    }
    #pragma unroll
    for (int m=0;m<4;++m)
      #pragma unroll
      for (int n=0;n<4;++n)
        acc[m][n] = __builtin_amdgcn_mfma_f32_16x16x32_bf16(af[m], bfr[n], acc[m][n], 0, 0, 0);

    if (more) {
      #pragma unroll
      for (int c=0;c<2;++c){
        short8 va, vb;
        #pragma unroll
        for (int j=0;j<4;++j){ va[j]=bf16b(a0[c][j]); va[4+j]=bf16b(a1[c][j]); }
        #pragma unroll
        for (int j=0;j<4;++j){ vb[j]=bf16b(b0[c][j]); vb[4+j]=bf16b(b1[c][j]); }
        *(short8*)((char*)As[cur^1] + sbyte[c]) = va;
        *(short8*)((char*)Bs[cur^1] + sbyte[c]) = vb;
      }
    }
    __syncthreads();
  }

  #pragma unroll
  for (int n=0;n<4;++n) {
    const int col = n0 + wc*64 + n*16 + l15;
    const float bv = bias[col];
    #pragma unroll
    for (int m=0;m<4;++m) {
      #pragma unroll
      for (int i=0;i<4;++i) {
        const int row = m0 + wr*64 + m*16 + lg*4 + i;
        C[(size_t)row*N + col] = bf16b((acc[m][n][i] + bv) * oscale);
      }
    }
  }
}

// ---------------- GEMM (out-projection): C = A(bf16) x W^T + bias ----------------
template<typename AT, typename OT>
__global__ __launch_bounds__(256)
void gemm_bt_kernel(const AT* __restrict__ A, const float* __restrict__ W,
                    const float* __restrict__ bias, OT* __restrict__ C,
                    int M, int N, int K, float oscale)
{
  __shared__ __align__(16) short As[2][128*32];
  __shared__ __align__(16) short Bs[2][128*32];
  const int t = threadIdx.x;
  const int lane = t & 63;
  const int wv = t >> 6;
  const int wr = wv >> 1, wc = wv & 1;
  const int l15 = lane & 15, lg = lane >> 4;

  const int id  = blockIdx.y * gridDim.x + blockIdx.x;
  const int nwg = gridDim.x * gridDim.y;
  const int wgid = (id & 7) * (nwg >> 3) + (id >> 3);
  const int bx = wgid >> 3;
  const int by = wgid & 7;
  const int m0 = bx * 128;
  const int n0 = by * 128;

  int srow[2], scol[2], sbyte[2];
  #pragma unroll
  for (int c=0;c<2;++c){
    const int e = t + c*256;
    srow[c] = e >> 2;
    scol[c] = (e & 3) * 8;
    sbyte[c] = srow[c]*64 + ((scol[c]*2) ^ ((srow[c]&6)<<3));
  }

  f32x4 acc[4][4] = {};

  #pragma unroll
  for (int c=0;c<2;++c){
    short8 va;
    if constexpr (std::is_same<AT,float>::value) {
      const float* src = A + (size_t)(m0+srow[c])*K + scol[c];
      f32x4 f0 = *(const f32x4*)src;
      f32x4 f1 = *(const f32x4*)(src+4);
      #pragma unroll
      for (int j=0;j<4;++j){ va[j]=bf16b(f0[j]); va[4+j]=bf16b(f1[j]); }
    } else {
      va = *(const short8*)(A + (size_t)(m0+srow[c])*K + scol[c]);
    }
    *(short8*)((char*)As[0] + sbyte[c]) = va;
    const float* sB = W + (size_t)(n0+srow[c])*K + scol[c];
    f32x4 g0 = *(const f32x4*)sB;
    f32x4 g1 = *(const f32x4*)(sB+4);
    short8 vb;
    #pragma unroll
    for (int j=0;j<4;++j){ vb[j]=bf16b(g0[j]); vb[4+j]=bf16b(g1[j]); }
    *(short8*)((char*)Bs[0] + sbyte[c]) = vb;
  }
  __syncthreads();

  const int NK = K >> 5;
  for (int ks = 0; ks < NK; ++ks) {
    const int cur = ks & 1;
    const bool more = (ks + 1 < NK);

    f32x4 a0[2], a1[2], b0[2], b1[2];
    short8 av[2];
    if (more) {
      const int k0 = (ks+1) << 5;
      #pragma unroll
      for (int c=0;c<2;++c){
        if constexpr (std::is_same<AT,float>::value) {
          const float* src = A + (size_t)(m0+srow[c])*K + k0 + scol[c];
          a0[c] = *(const f32x4*)src;
          a1[c] = *(const f32x4*)(src+4);
        } else {
          av[c] = *(const short8*)(A + (size_t)(m0+srow[c])*K + k0 + scol[c]);
        }
        const float* sB = W + (size_t)(n0+srow[c])*K + k0 + scol[c];
        b0[c] = *(const f32x4*)sB;
        b1[c] = *(const f32x4*)(sB+4);
      }
    }

    short8 af[4], bfr[4];
    #pragma unroll
    for (int m=0;m<4;++m) {
      const int row = wr*64 + m*16 + l15;
      af[m] = *(const short8*)((const char*)As[cur] + row*64 + ((lg*16) ^ ((row&6)<<3)));
    }
    #pragma unroll
    for (int n=0;n<4;++n) {
      const int row = wc*64 + n*16 + l15;
      bfr[n] = *(const short8*)((const char*)Bs[cur] + row*64 + ((lg*16) ^ ((row&6)<<3)));
    }
    #pragma unroll
    for (int m=0;m<4;++m)
      #pragma unroll
      for (int n=0;n<4;++n)
        acc[m][n] = __builtin_amdgcn_mfma_f32_16x16x32_bf16(af[m], bfr[n], acc[m][n], 0, 0, 0);

    if (more) {
      #pragma unroll
      for (int c=0;c<2;++c){
        short8 va;
        if constexpr (std::is_same<AT,float>::value) {
          #pragma unroll
          for (int j=0;j<4;++j){ va[j]=bf16b(a0[c][j]); va[4+j]=bf16b(a1[c][j]); }
        } else {
          va = av[c];
        }
        *(short8*)((char*)As[cur^1] + sbyte[c]) = va;
        short8 vb;
        #pragma unroll
        for (int j=0;j<4;++j){ vb[j]=bf16b(b0[c][j]); vb[4+j]=bf16b(b1[c][j]); }
        *(short8*)((char*)Bs[cur^1] + sbyte[c]) = vb;
      }
    }
    __syncthreads();
  }

  #pragma unroll
  for (int n=0;n<4;++n) {
    const int col = n0 + wc*64 + n*16 + l15;
    const float bv = bias[col];
    #pragma unroll
    for (int m=0;m<4;++m) {
      #pragma unroll
      for (int i=0;i<4;++i) {
        const int row = m0 + wr*64 + m*16 + lg*4 + i;
        const float val = (acc[m][n][i] + bv) * oscale;
        if constexpr (std::is_same<OT,float>::value) C[(size_t)row*N + col] = val;
        else                                         C[(size_t)row*N + col] = bf16b(val);
      }
    }
  }
}

// ---------------- mask scan: per batch, ordered indices of unmasked keys ----
__global__ __launch_bounds__(256)
void scan_kernel(const int* __restrict__ mask, int* __restrict__ IDX, int* __restrict__ cnt)
{
  const int b = blockIdx.x;
  const int t = threadIdx.x;
  const int* m = mask + (size_t)b*4096;
  __shared__ int psum[256];
  int loc[16]; int c = 0;
  const int base = t*16;
  #pragma unroll
  for (int j=0;j<16;++j){ loc[j] = (m[base+j] != 0) ? 1 : 0; c += loc[j]; }
  psum[t] = c;
  __syncthreads();
  for (int off=1; off<256; off<<=1){
    int add = (t >= off) ? psum[t-off] : 0;
    __syncthreads();
    psum[t] += add;
    __syncthreads();
  }
  int j2 = psum[t] - c;
  #pragma unroll
  for (int j=0;j<16;++j)
    if (loc[j]) IDX[(size_t)b*4096 + (j2++)] = base + j;
  if (t == 255) cnt[b] = psum[255];
}

// ---------------- K gather: compact K rows (contiguous KC), pads zeroed -------
__global__ __launch_bounds__(256)
void kgather_kernel(const short* __restrict__ KH, const int* __restrict__ IDX,
                    const int* __restrict__ cnt, short* __restrict__ KC)
{
  const int b = blockIdx.y;
  const int c = cnt[b];
  const int rc = (c + 63) & ~63;
  const int g = threadIdx.x >> 4;
  const int l = threadIdx.x & 15;
  const int j = blockIdx.x*16 + g;
  if (j >= rc) return;
  const size_t dst = ((size_t)b*4096 + j)*1024;
  if (j < c) {
    const int i = IDX[(size_t)b*4096 + j];
    const size_t src = ((size_t)b*4096 + i)*1024;
    #pragma unroll
    for (int ch=0; ch<8; ++ch)
      *(short8*)(KC + dst + ch*128 + l*8) = *(const short8*)(KH + src + ch*128 + l*8);
  } else {
    short8 z = {};
    #pragma unroll
    for (int ch=0; ch<8; ++ch)
      *(short8*)(KC + dst + ch*128 + l*8) = z;
  }
}

// ---------------- V transpose (gathering): VH rows IDX[j] -> Vt[(bh)*64+dk][j] ----
__global__ __launch_bounds__(256)
void transpose_v_kernel(const short* __restrict__ Vh, short* __restrict__ Vt,
                        const int* __restrict__ IDX, const int* __restrict__ cnt)
{
  __shared__ short tile[64][65];
  const int t = threadIdx.x;
  const int bh = blockIdx.y, b = bh >> 4, h = bh & 15;
  const int s0 = blockIdx.x * 64;
  const int c = cnt[b];
  if (s0 >= ((c + 63) & ~63)) return;
  const int r = t >> 2;
  const int cc = (t & 3) * 16;
  short8 v0 = {}, v1 = {};
  if (s0 + r < c) {
    const int srcRow = IDX[(size_t)b*4096 + s0 + r];
    const short* src = Vh + (size_t)(b*4096 + srcRow)*1024 + h*64 + cc;
    v0 = *(const short8*)src;
    v1 = *(const short8*)(src + 8);
  }
  #pragma unroll
  for (int j=0;j<8;++j){ tile[r][cc+j]=v0[j]; tile[r][cc+8+j]=v1[j]; }
  __syncthreads();
  short8 o0, o1;
  #pragma unroll
  for (int j=0;j<8;++j){ o0[j]=tile[cc+j][r]; o1[j]=tile[cc+8+j][r]; }
  short* dst = Vt + (size_t)(bh*64 + r)*4096 + s0 + cc;
  *(short8*)dst = o0;
  *(short8*)(dst+8) = o1;
}

// ---------------- Flash attention over compacted keys (contiguous KC) ---------
__global__ __launch_bounds__(256, 2)
void flash_kernel(const short* __restrict__ Qh, const short* __restrict__ Kh,
                  const short* __restrict__ Vt,
                  const int* __restrict__ cnt, short* __restrict__ O)
{
  __shared__ __align__(16) char smem[32768];
  char* KsBufB = smem;
  char* VsBufB = smem + 16384;

  const int t = threadIdx.x;
  const int lane = t & 63, wv = t >> 6;
  const int l31 = lane & 31, hi = lane >> 5;
  const int rsw = (l31 & 7) << 4;
  const int bh = blockIdx.y, b = bh >> 4, h = bh & 15;
  const int q0 = blockIdx.x * 256;
  const bool lo = (lane < 32);

  const int cB = cnt[b];
  const int NT = (cB + 63) >> 6;

  short8 qf[2][4];
  #pragma unroll
  for (int qh=0; qh<2; ++qh) {
    const short* qrow = Qh + (size_t)(b*4096 + q0 + wv*64 + qh*32 + l31)*1024 + h*64;
    #pragma unroll
    for (int ds=0; ds<4; ++ds)
      qf[qh][ds] = *(const short8*)(qrow + ds*16 + hi*8);
  }

  float l_run[2] = {0.0f, 0.0f};
  f32x16 oA[2][2] = {};

  #pragma unroll
  for (int c = 0; c < 2; ++c) {
    const int e = t + c*256;
    const int row = e >> 3, sl = e & 7;
    const int byte = row*128 + ((sl*16) ^ ((row&7)<<4));
    *(short8*)(KsBufB + byte) =
      *(const short8*)(Kh + (size_t)(b*4096 + row)*1024 + h*64 + sl*8);
    *(short8*)(VsBufB + byte) =
      *(const short8*)(Vt + (size_t)(bh*64 + row)*4096 + sl*8);
  }
  __syncthreads();

  for (int kt = 0; kt < NT; ++kt) {
    const int cur = kt & 1;
    const char* KsC = KsBufB + cur*8192;
    const char* VsC = VsBufB + cur*8192;
    const bool more = (kt + 1 < NT);

    f32x16 sA[2][2];
    if (more) {
      #pragma unroll
      for (int qh=0;qh<2;++qh)
        #pragma unroll
        for (int kh=0;kh<2;++kh)
          sA[qh][kh] = (f32x16){};
    } else {
      const int kbase = kt*64 - cB;
      #pragma unroll
      for (int kh=0;kh<2;++kh)
        #pragma unroll
        for (int r=0;r<16;++r) {
          const int key = kh*32 + (r>>2)*8 + hi*4 + (r&3);
          const float mv = (kbase + key < 0) ? 0.0f : -1.0e9f;
          sA[0][kh][r] = mv;
          sA[1][kh][r] = mv;
        }
    }

    __builtin_amdgcn_s_setprio(1);
    #pragma unroll
    for (int ds=0; ds<4; ++ds) {
      short8 kf0 = *(const short8*)(KsC + l31*128       + ((ds*32 + hi*16) ^ rsw));
      short8 kf1 = *(const short8*)(KsC + (l31+32)*128  + ((ds*32 + hi*16) ^ rsw));
      sA[0][0] = __builtin_amdgcn_mfma_f32_32x32x16_bf16(kf0, qf[0][ds], sA[0][0], 0,0,0);
      sA[0][1] = __builtin_amdgcn_mfma_f32_32x32x16_bf16(kf1, qf[0][ds], sA[0][1], 0,0,0);
      sA[1][0] = __builtin_amdgcn_mfma_f32_32x32x16_bf16(kf0, qf[1][ds], sA[1][0], 0,0,0);
      sA[1][1] = __builtin_amdgcn_mfma_f32_32x32x16_bf16(kf1, qf[1][ds], sA[1][1], 0,0,0);
    }
    __builtin_amdgcn_s_setprio(0);

    short8 nk[2], nv[2];
    if (more) {
      #pragma unroll
      for (int c=0;c<2;++c){
        const int e = t + c*256; const int row = e>>3, sl = e&7;
        nk[c] = *(const short8*)(Kh + (size_t)(b*4096 + (kt+1)*64 + row)*1024 + h*64 + sl*8);
        nv[c] = *(const short8*)(Vt + (size_t)(bh*64 + row)*4096 + (kt+1)*64 + sl*8);
      }
    }

    #pragma unroll
    for (int qh=0; qh<2; ++qh) {
      f32x4 lp = {0.f,0.f,0.f,0.f};
      #pragma unroll
      for (int kh=0;kh<2;++kh)
        #pragma unroll
        for (int r=0;r<16;++r) {
          const float p = exp2a(sA[qh][kh][r]);
          sA[qh][kh][r] = p;
          lp[r&3] += p;
        }
      l_run[qh] += (lp[0]+lp[1]) + (lp[2]+lp[3]);
    }

    __builtin_amdgcn_s_setprio(1);
    #pragma unroll
    for (int tt=0;tt<4;++tt) {
      const int kh = tt>>1, ro = (tt&1)*8;
      unsigned w0[4], w1[4];
      {
        unsigned c01 = cvtpk(sA[0][kh][ro+0], sA[0][kh][ro+1]);
        unsigned c23 = cvtpk(sA[0][kh][ro+2], sA[0][kh][ro+3]);
        unsigned c45 = cvtpk(sA[0][kh][ro+4], sA[0][kh][ro+5]);
        unsigned c67 = cvtpk(sA[0][kh][ro+6], sA[0][kh][ro+7]);
        uint2v r02 = plswap(c01, c45);
        uint2v r13 = plswap(c23, c67);
        w0[0]=r02[0]; w0[1]=r13[0]; w0[2]=r02[1]; w0[3]=r13[1];
      }
      {
        unsigned c01 = cvtpk(sA[1][kh][ro+0], sA[1][kh][ro+1]);
        unsigned c23 = cvtpk(sA[1][kh][ro+2], sA[1][kh][ro+3]);
        unsigned c45 = cvtpk(sA[1][kh][ro+4], sA[1][kh][ro+5]);
        unsigned c67 = cvtpk(sA[1][kh][ro+6], sA[1][kh][ro+7]);
        uint2v r02 = plswap(c01, c45);
        uint2v r13 = plswap(c23, c67);
        w1[0]=r02[0]; w1[1]=r13[0]; w1[2]=r02[1]; w1[3]=r13[1];
      }
      #pragma unroll
      for (int n=0;n<2;++n) {
        short8 vf = *(const short8*)(VsC + (n*32+l31)*128 + ((tt*32 + hi*16) ^ rsw));
        uint4v wp0 = {w0[0], w0[1], w0[2], w0[3]};
        uint4v wp1 = {w1[0], w1[1], w1[2], w1[3]};
        oA[0][n] = __builtin_amdgcn_mfma_f32_32x32x16_bf16(vf, __builtin_bit_cast(short8, wp0), oA[0][n], 0,0,0);
        oA[1][n] = __builtin_amdgcn_mfma_f32_32x32x16_bf16(vf, __builtin_bit_cast(short8, wp1), oA[1][n], 0,0,0);
      }
    }
    __builtin_amdgcn_s_setprio(0);

    if (more) {
      #pragma unroll
      for (int c=0;c<2;++c){
        const int e = t + c*256; const int row = e>>3, sl = e&7;
        const int byte = row*128 + ((sl*16) ^ ((row&7)<<4));
        *(short8*)(KsBufB + (cur^1)*8192 + byte) = nk[c];
        *(short8*)(VsBufB + (cur^1)*8192 + byte) = nv[c];
      }
    }
    __syncthreads();
  }

  char* ot = smem + wv*4096;
  #pragma unroll
  for (int qh=0; qh<2; ++qh) {
    float lr = l_run[qh];
    {
      uint2v rl = plswap(__builtin_bit_cast(unsigned, lr), __builtin_bit_cast(unsigned, lr));
      lr += __builtin_bit_cast(float, lo ? rl[1] : rl[0]);
    }
    const float inv = 1.0f / lr;
    #pragma unroll
    for (int n=0;n<2;++n)
      #pragma unroll
      for (int rq=0;rq<4;++rq) {
        const unsigned w0 = cvtpk(oA[qh][n][rq*4+0]*inv, oA[qh][n][rq*4+1]*inv);
        const unsigned w1 = cvtpk(oA[qh][n][rq*4+2]*inv, oA[qh][n][rq*4+3]*inv);
        const int sl = n*4 + rq;
        const int byte = l31*128 + ((sl*16) ^ ((l31&7)<<4)) + hi*8;
        *(unsigned*)(ot + byte)     = w0;
        *(unsigned*)(ot + byte + 4) = w1;
      }
    asm volatile("s_waitcnt lgkmcnt(0)" ::: "memory");
    __builtin_amdgcn_sched_barrier(0);

    const int row = lane >> 1, half = lane & 1;
    const int orow = b*4096 + q0 + wv*64 + qh*32 + row;
    #pragma unroll
    for (int i=0;i<4;++i) {
      const int sl = half*4 + i;
      short8 vv = *(const short8*)(ot + row*128 + ((sl*16) ^ ((row&7)<<4)));
      *(short8*)(O + (size_t)orow*1024 + h*64 + half*32 + i*8) = vv;
    }
    asm volatile("s_waitcnt lgkmcnt(0)" ::: "memory");
    __builtin_amdgcn_sched_barrier(0);
  }
}

extern "C" void kernel_launch(void* const* d_in, const int* in_sizes, int n_in,
                              void* d_out, int out_size, void* d_ws, size_t ws_size,
                              hipStream_t stream)
{
  const float* q    = (const float*)d_in[0];
  const float* k    = (const float*)d_in[1];
  const float* v    = (const float*)d_in[2];
  const int*   mask = (const int*)d_in[3];
  const float* w_q  = (const float*)d_in[4];
  const float* b_q  = (const float*)d_in[5];
  const float* w_k  = (const float*)d_in[6];
  const float* b_k  = (const float*)d_in[7];
  const float* w_v  = (const float*)d_in[8];
  const float* b_v  = (const float*)d_in[9];
  const float* w_o  = (const float*)d_in[10];
  const float* b_o  = (const float*)d_in[11];
  float* out = (float*)d_out;

  char* ws = (char*)d_ws;
  const size_t SZ = (size_t)8192*1024*2;   // one bf16 [8192][1024] buffer = 16MB
  short* QH = (short*)(ws);
  short* KH = (short*)(ws + SZ);
  short* OB = (short*)(ws + 2*SZ);         // V-proj output, then reused for attn out
  short* VT = (short*)(ws + 3*SZ);
  short* KC = (short*)(ws + 4*SZ);         // compacted K (ws >= 96MB proven in R16)
  int*   IDX = (int*)(ws + 5*SZ);          // 32KB
  int*   CNT = (int*)(ws + 5*SZ + 32768);  // 8B
  short* VH = OB;

  const float QSCALE = 0.125f * 1.44269504f;

  QKVArgs qa;
  qa.aq = q;   qa.ak = k;   qa.av = v;
  qa.wq = w_q; qa.wk = w_k; qa.wv = w_v;
  qa.bq = b_q; qa.bk = b_k; qa.bv = b_v;
  qa.cq = QH;  qa.ck = KH;  qa.cv = VH;
  qa.sq = QSCALE; qa.sk = 1.0f; qa.sv = 1.0f;

  dim3 bG(256);
  hipLaunchKernelGGL(qkv_gemm_kernel, dim3(64, 8, 3), bG, 0, stream, qa, 8192, 1024, 1024);
  hipLaunchKernelGGL(scan_kernel, dim3(2), bG, 0, stream, mask, IDX, CNT);
  hipLaunchKernelGGL(kgather_kernel, dim3(256, 2), bG, 0, stream, KH, IDX, CNT, KC);
  hipLaunchKernelGGL(transpose_v_kernel, dim3(64, 32), bG, 0, stream, VH, VT, IDX, CNT);
  hipLaunchKernelGGL(flash_kernel, dim3(16, 32), bG, 0, stream, QH, KC, VT, CNT, OB);
  hipLaunchKernelGGL((gemm_bt_kernel<short, float>), dim3(64, 8), bG, 0, stream, OB, w_o, b_o, out, 8192, 1024, 1024, 1.0f);
}

// Round 22
// 203.038 us; speedup vs baseline: 1.1663x; 1.0084x over previous
//
#include <hip/hip_runtime.h>
#include <hip/hip_bf16.h>
#include <stdint.h>
#include <type_traits>

typedef __attribute__((ext_vector_type(8))) short short8;
typedef __attribute__((ext_vector_type(4))) float f32x4;
typedef __attribute__((ext_vector_type(16))) float f32x16;
typedef __attribute__((ext_vector_type(4))) unsigned int uint4v;
typedef __attribute__((ext_vector_type(2))) unsigned int uint2v;

#define DEV static __device__ __forceinline__

DEV short bf16b(float f) {
  return __builtin_bit_cast(short, __float2bfloat16(f));
}
DEV float exp2a(float x){ float r; asm("v_exp_f32 %0, %1" : "=v"(r) : "v"(x)); return r; }
DEV unsigned cvtpk(float lo, float hi){ unsigned r; asm("v_cvt_pk_bf16_f32 %0, %1, %2" : "=v"(r) : "v"(lo), "v"(hi)); return r; }
// permlane32_swap BUILTIN (R8-verified). swap(a,b) -> { [a.lo|b.lo], [a.hi|b.hi] }.
DEV uint2v plswap(unsigned a, unsigned b){
  return __builtin_amdgcn_permlane32_swap(a, b, false, false);
}

// ================= fused QKV projection GEMM (BM=128, R19-verified) =============
struct QKVArgs {
  const float *aq, *ak, *av;
  const float *wq, *wk, *wv;
  const float *bq, *bk, *bv;
  short *cq, *ck, *cv;
  float sq, sk, sv;
};

__global__ __launch_bounds__(256)
void qkv_gemm_kernel(QKVArgs a, int M, int N, int K)
{
  __shared__ __align__(16) short As[2][128*32];
  __shared__ __align__(16) short Bs[2][128*32];
  const int t = threadIdx.x;
  const int lane = t & 63;
  const int wv = t >> 6;
  const int wr = wv >> 1, wc = wv & 1;
  const int l15 = lane & 15, lg = lane >> 4;

  const int z = blockIdx.z;
  const float* A    = (z==0) ? a.aq : (z==1) ? a.ak : a.av;
  const float* W    = (z==0) ? a.wq : (z==1) ? a.wk : a.wv;
  const float* bias = (z==0) ? a.bq : (z==1) ? a.bk : a.bv;
  short* C          = (z==0) ? a.cq : (z==1) ? a.ck : a.cv;
  const float oscale= (z==0) ? a.sq : (z==1) ? a.sk : a.sv;

  const int id  = blockIdx.y * gridDim.x + blockIdx.x;
  const int nwg = gridDim.x * gridDim.y;          // 512, divisible by 8
  const int wgid = (id & 7) * (nwg >> 3) + (id >> 3);
  const int bx = wgid >> 3;                        // gridDim.y == 8
  const int by = wgid & 7;
  const int m0 = bx * 128;
  const int n0 = by * 128;

  int srow[2], scol[2], sbyte[2];
  #pragma unroll
  for (int c=0;c<2;++c){
    const int e = t + c*256;
    srow[c] = e >> 2;
    scol[c] = (e & 3) * 8;
    sbyte[c] = srow[c]*64 + ((scol[c]*2) ^ ((srow[c]&6)<<3));
  }

  f32x4 acc[4][4] = {};

  #pragma unroll
  for (int c=0;c<2;++c){
    const float* src = A + (size_t)(m0+srow[c])*K + scol[c];
    f32x4 f0 = *(const f32x4*)src;
    f32x4 f1 = *(const f32x4*)(src+4);
    short8 va;
    #pragma unroll
    for (int j=0;j<4;++j){ va[j]=bf16b(f0[j]); va[4+j]=bf16b(f1[j]); }
    *(short8*)((char*)As[0] + sbyte[c]) = va;
    const float* sB = W + (size_t)(n0+srow[c])*K + scol[c];
    f32x4 g0 = *(const f32x4*)sB;
    f32x4 g1 = *(const f32x4*)(sB+4);
    short8 vb;
    #pragma unroll
    for (int j=0;j<4;++j){ vb[j]=bf16b(g0[j]); vb[4+j]=bf16b(g1[j]); }
    *(short8*)((char*)Bs[0] + sbyte[c]) = vb;
  }
  __syncthreads();

  const int NK = K >> 5;
  for (int ks = 0; ks < NK; ++ks) {
    const int cur = ks & 1;
    const bool more = (ks + 1 < NK);

    f32x4 a0[2], a1[2], b0[2], b1[2];
    if (more) {
      const int k0 = (ks+1) << 5;
      #pragma unroll
      for (int c=0;c<2;++c){
        const float* src = A + (size_t)(m0+srow[c])*K + k0 + scol[c];
        a0[c] = *(const f32x4*)src;
        a1[c] = *(const f32x4*)(src+4);
        const float* sB = W + (size_t)(n0+srow[c])*K + k0 + scol[c];
        b0[c] = *(const f32x4*)sB;
        b1[c] = *(const f32x4*)(sB+4);
      }
    }

    short8 af[4], bfr[4];
    #pragma unroll
    for (int m=0;m<4;++m) {
      const int row = wr*64 + m*16 + l15;
      af[m] = *(const short8*)((const char*)As[cur] + row*64 + ((lg*16) ^ ((row&6)<<3)));
    }
    #pragma unroll
    for (int n=0;n<4;++n) {
      const int row = wc*64 + n*16 + l15;
      bfr[n] = *(const short8*)((const char*)Bs[cur] + row*64 + ((lg*16) ^ ((row&6)<<3)));
    }
    #pragma unroll
    for (int m=0;m<4;++m)
      #pragma unroll
      for (int n=0;n<4;++n)
        acc[m][n] = __builtin_amdgcn_mfma_f32_16x16x32_bf16(af[m], bfr[n], acc[m][n], 0, 0, 0);

    if (more) {
      #pragma unroll
      for (int c=0;c<2;++c){
        short8 va, vb;
        #pragma unroll
        for (int j=0;j<4;++j){ va[j]=bf16b(a0[c][j]); va[4+j]=bf16b(a1[c][j]); }
        #pragma unroll
        for (int j=0;j<4;++j){ vb[j]=bf16b(b0[c][j]); vb[4+j]=bf16b(b1[c][j]); }
        *(short8*)((char*)As[cur^1] + sbyte[c]) = va;
        *(short8*)((char*)Bs[cur^1] + sbyte[c]) = vb;
      }
    }
    __syncthreads();
  }

  #pragma unroll
  for (int n=0;n<4;++n) {
    const int col = n0 + wc*64 + n*16 + l15;
    const float bv = bias[col];
    #pragma unroll
    for (int m=0;m<4;++m) {
      #pragma unroll
      for (int i=0;i<4;++i) {
        const int row = m0 + wr*64 + m*16 + lg*4 + i;
        C[(size_t)row*N + col] = bf16b((acc[m][n][i] + bv) * oscale);
      }
    }
  }
}

// ---------------- GEMM (out-projection): C = A(bf16) x W^T + bias ----------------
template<typename AT, typename OT>
__global__ __launch_bounds__(256)
void gemm_bt_kernel(const AT* __restrict__ A, const float* __restrict__ W,
                    const float* __restrict__ bias, OT* __restrict__ C,
                    int M, int N, int K, float oscale)
{
  __shared__ __align__(16) short As[2][128*32];
  __shared__ __align__(16) short Bs[2][128*32];
  const int t = threadIdx.x;
  const int lane = t & 63;
  const int wv = t >> 6;
  const int wr = wv >> 1, wc = wv & 1;
  const int l15 = lane & 15, lg = lane >> 4;

  const int id  = blockIdx.y * gridDim.x + blockIdx.x;
  const int nwg = gridDim.x * gridDim.y;
  const int wgid = (id & 7) * (nwg >> 3) + (id >> 3);
  const int bx = wgid >> 3;
  const int by = wgid & 7;
  const int m0 = bx * 128;
  const int n0 = by * 128;

  int srow[2], scol[2], sbyte[2];
  #pragma unroll
  for (int c=0;c<2;++c){
    const int e = t + c*256;
    srow[c] = e >> 2;
    scol[c] = (e & 3) * 8;
    sbyte[c] = srow[c]*64 + ((scol[c]*2) ^ ((srow[c]&6)<<3));
  }

  f32x4 acc[4][4] = {};

  #pragma unroll
  for (int c=0;c<2;++c){
    short8 va;
    if constexpr (std::is_same<AT,float>::value) {
      const float* src = A + (size_t)(m0+srow[c])*K + scol[c];
      f32x4 f0 = *(const f32x4*)src;
      f32x4 f1 = *(const f32x4*)(src+4);
      #pragma unroll
      for (int j=0;j<4;++j){ va[j]=bf16b(f0[j]); va[4+j]=bf16b(f1[j]); }
    } else {
      va = *(const short8*)(A + (size_t)(m0+srow[c])*K + scol[c]);
    }
    *(short8*)((char*)As[0] + sbyte[c]) = va;
    const float* sB = W + (size_t)(n0+srow[c])*K + scol[c];
    f32x4 g0 = *(const f32x4*)sB;
    f32x4 g1 = *(const f32x4*)(sB+4);
    short8 vb;
    #pragma unroll
    for (int j=0;j<4;++j){ vb[j]=bf16b(g0[j]); vb[4+j]=bf16b(g1[j]); }
    *(short8*)((char*)Bs[0] + sbyte[c]) = vb;
  }
  __syncthreads();

  const int NK = K >> 5;
  for (int ks = 0; ks < NK; ++ks) {
    const int cur = ks & 1;
    const bool more = (ks + 1 < NK);

    f32x4 a0[2], a1[2], b0[2], b1[2];
    short8 av[2];
    if (more) {
      const int k0 = (ks+1) << 5;
      #pragma unroll
      for (int c=0;c<2;++c){
        if constexpr (std::is_same<AT,float>::value) {
          const float* src = A + (size_t)(m0+srow[c])*K + k0 + scol[c];
          a0[c] = *(const f32x4*)src;
          a1[c] = *(const f32x4*)(src+4);
        } else {
          av[c] = *(const short8*)(A + (size_t)(m0+srow[c])*K + k0 + scol[c]);
        }
        const float* sB = W + (size_t)(n0+srow[c])*K + k0 + scol[c];
        b0[c] = *(const f32x4*)sB;
        b1[c] = *(const f32x4*)(sB+4);
      }
    }

    short8 af[4], bfr[4];
    #pragma unroll
    for (int m=0;m<4;++m) {
      const int row = wr*64 + m*16 + l15;
      af[m] = *(const short8*)((const char*)As[cur] + row*64 + ((lg*16) ^ ((row&6)<<3)));
    }
    #pragma unroll
    for (int n=0;n<4;++n) {
      const int row = wc*64 + n*16 + l15;
      bfr[n] = *(const short8*)((const char*)Bs[cur] + row*64 + ((lg*16) ^ ((row&6)<<3)));
    }
    #pragma unroll
    for (int m=0;m<4;++m)
      #pragma unroll
      for (int n=0;n<4;++n)
        acc[m][n] = __builtin_amdgcn_mfma_f32_16x16x32_bf16(af[m], bfr[n], acc[m][n], 0, 0, 0);

    if (more) {
      #pragma unroll
      for (int c=0;c<2;++c){
        short8 va;
        if constexpr (std::is_same<AT,float>::value) {
          #pragma unroll
          for (int j=0;j<4;++j){ va[j]=bf16b(a0[c][j]); va[4+j]=bf16b(a1[c][j]); }
        } else {
          va = av[c];
        }
        *(short8*)((char*)As[cur^1] + sbyte[c]) = va;
        short8 vb;
        #pragma unroll
        for (int j=0;j<4;++j){ vb[j]=bf16b(b0[c][j]); vb[4+j]=bf16b(b1[c][j]); }
        *(short8*)((char*)Bs[cur^1] + sbyte[c]) = vb;
      }
    }
    __syncthreads();
  }

  #pragma unroll
  for (int n=0;n<4;++n) {
    const int col = n0 + wc*64 + n*16 + l15;
    const float bv = bias[col];
    #pragma unroll
    for (int m=0;m<4;++m) {
      #pragma unroll
      for (int i=0;i<4;++i) {
        const int row = m0 + wr*64 + m*16 + lg*4 + i;
        const float val = (acc[m][n][i] + bv) * oscale;
        if constexpr (std::is_same<OT,float>::value) C[(size_t)row*N + col] = val;
        else                                         C[(size_t)row*N + col] = bf16b(val);
      }
    }
  }
}

// ================= fused prep: per-block scan + {K-gather | V-transpose} ========
// Replaces scan_kernel + kgather_kernel + transpose_v_kernel (3 launches -> 1).
// Every block recomputes its batch's prefix-scan into LDS (mask is 32KB,
// L2-hot; ~1-2us aggregate) — removes the cross-block IDX dependency.
// Blocks 0..511: K-gather role (b = x>>8, xb = x&255).
// Blocks 512..2559: V-transpose role (i = x-512, bh = i>>6, s0 = (i&63)*64).
__global__ __launch_bounds__(256)
void prep_kernel(const int* __restrict__ mask,
                 const short* __restrict__ KH, const short* __restrict__ VH,
                 short* __restrict__ KC, short* __restrict__ Vt,
                 int* __restrict__ CNT)
{
  __shared__ int idxs[4096];
  __shared__ int psum[256];
  __shared__ short tile[64][65];

  const int t = threadIdx.x;
  const int x = blockIdx.x;
  const bool isK = (x < 512);
  const int i_tr = x - 512;
  const int bh = isK ? 0 : (i_tr >> 6);
  const int b  = isK ? (x >> 8) : (bh >> 4);

  // ---- per-block scan (identical algorithm to the verified scan_kernel) ----
  const int* m = mask + (size_t)b*4096;
  int loc[16]; int c = 0;
  const int base = t*16;
  #pragma unroll
  for (int j=0;j<16;++j){ loc[j] = (m[base+j] != 0) ? 1 : 0; c += loc[j]; }
  psum[t] = c;
  __syncthreads();
  for (int off=1; off<256; off<<=1){
    int add = (t >= off) ? psum[t-off] : 0;
    __syncthreads();
    psum[t] += add;
    __syncthreads();
  }
  int j2 = psum[t] - c;
  #pragma unroll
  for (int j=0;j<16;++j)
    if (loc[j]) idxs[j2++] = base + j;
  __syncthreads();
  const int cnt = psum[255];
  const int rc = (cnt + 63) & ~63;

  if (isK) {
    if ((x & 255) == 0 && t == 0) CNT[b] = cnt;   // two writers, b=0 and b=1
    // ---- K gather: 16 rows per block, 16 lanes per row ----
    const int g = t >> 4;
    const int l = t & 15;
    const int j = (x & 255)*16 + g;
    if (j < rc) {
      const size_t dst = ((size_t)b*4096 + j)*1024;
      if (j < cnt) {
        const int src_i = idxs[j];
        const size_t src = ((size_t)b*4096 + src_i)*1024;
        #pragma unroll
        for (int ch=0; ch<8; ++ch)
          *(short8*)(KC + dst + ch*128 + l*8) = *(const short8*)(KH + src + ch*128 + l*8);
      } else {
        short8 z = {};
        #pragma unroll
        for (int ch=0; ch<8; ++ch)
          *(short8*)(KC + dst + ch*128 + l*8) = z;
      }
    }
  } else {
    // ---- V transpose (gathering): 64 seq rows x 64 dk -> Vt[bh*64+dk][s] ----
    const int h = bh & 15;
    const int s0 = (i_tr & 63) * 64;
    if (s0 >= rc) return;
    const int r = t >> 2;
    const int cc = (t & 3) * 16;
    short8 v0 = {}, v1 = {};
    if (s0 + r < cnt) {
      const int srcRow = idxs[s0 + r];
      const short* src = VH + (size_t)(b*4096 + srcRow)*1024 + h*64 + cc;
      v0 = *(const short8*)src;
      v1 = *(const short8*)(src + 8);
    }
    #pragma unroll
    for (int j=0;j<8;++j){ tile[r][cc+j]=v0[j]; tile[r][cc+8+j]=v1[j]; }
    __syncthreads();
    short8 o0, o1;
    #pragma unroll
    for (int j=0;j<8;++j){ o0[j]=tile[cc+j][r]; o1[j]=tile[cc+8+j][r]; }
    short* dst = Vt + (size_t)(bh*64 + r)*4096 + s0 + cc;
    *(short8*)dst = o0;
    *(short8*)(dst+8) = o1;
  }
}

// ---------------- Flash attention over compacted keys (contiguous KC) ---------
__global__ __launch_bounds__(256, 2)
void flash_kernel(const short* __restrict__ Qh, const short* __restrict__ Kh,
                  const short* __restrict__ Vt,
                  const int* __restrict__ cnt, short* __restrict__ O)
{
  __shared__ __align__(16) char smem[32768];
  char* KsBufB = smem;
  char* VsBufB = smem + 16384;

  const int t = threadIdx.x;
  const int lane = t & 63, wv = t >> 6;
  const int l31 = lane & 31, hi = lane >> 5;
  const int rsw = (l31 & 7) << 4;
  const int bh = blockIdx.y, b = bh >> 4, h = bh & 15;
  const int q0 = blockIdx.x * 256;
  const bool lo = (lane < 32);

  const int cB = cnt[b];
  const int NT = (cB + 63) >> 6;

  short8 qf[2][4];
  #pragma unroll
  for (int qh=0; qh<2; ++qh) {
    const short* qrow = Qh + (size_t)(b*4096 + q0 + wv*64 + qh*32 + l31)*1024 + h*64;
    #pragma unroll
    for (int ds=0; ds<4; ++ds)
      qf[qh][ds] = *(const short8*)(qrow + ds*16 + hi*8);
  }

  float l_run[2] = {0.0f, 0.0f};
  f32x16 oA[2][2] = {};

  #pragma unroll
  for (int c = 0; c < 2; ++c) {
    const int e = t + c*256;
    const int row = e >> 3, sl = e & 7;
    const int byte = row*128 + ((sl*16) ^ ((row&7)<<4));
    *(short8*)(KsBufB + byte) =
      *(const short8*)(Kh + (size_t)(b*4096 + row)*1024 + h*64 + sl*8);
    *(short8*)(VsBufB + byte) =
      *(const short8*)(Vt + (size_t)(bh*64 + row)*4096 + sl*8);
  }
  __syncthreads();

  for (int kt = 0; kt < NT; ++kt) {
    const int cur = kt & 1;
    const char* KsC = KsBufB + cur*8192;
    const char* VsC = VsBufB + cur*8192;
    const bool more = (kt + 1 < NT);

    f32x16 sA[2][2];
    if (more) {
      #pragma unroll
      for (int qh=0;qh<2;++qh)
        #pragma unroll
        for (int kh=0;kh<2;++kh)
          sA[qh][kh] = (f32x16){};
    } else {
      const int kbase = kt*64 - cB;
      #pragma unroll
      for (int kh=0;kh<2;++kh)
        #pragma unroll
        for (int r=0;r<16;++r) {
          const int key = kh*32 + (r>>2)*8 + hi*4 + (r&3);
          const float mv = (kbase + key < 0) ? 0.0f : -1.0e9f;
          sA[0][kh][r] = mv;
          sA[1][kh][r] = mv;
        }
    }

    __builtin_amdgcn_s_setprio(1);
    #pragma unroll
    for (int ds=0; ds<4; ++ds) {
      short8 kf0 = *(const short8*)(KsC + l31*128       + ((ds*32 + hi*16) ^ rsw));
      short8 kf1 = *(const short8*)(KsC + (l31+32)*128  + ((ds*32 + hi*16) ^ rsw));
      sA[0][0] = __builtin_amdgcn_mfma_f32_32x32x16_bf16(kf0, qf[0][ds], sA[0][0], 0,0,0);
      sA[0][1] = __builtin_amdgcn_mfma_f32_32x32x16_bf16(kf1, qf[0][ds], sA[0][1], 0,0,0);
      sA[1][0] = __builtin_amdgcn_mfma_f32_32x32x16_bf16(kf0, qf[1][ds], sA[1][0], 0,0,0);
      sA[1][1] = __builtin_amdgcn_mfma_f32_32x32x16_bf16(kf1, qf[1][ds], sA[1][1], 0,0,0);
    }
    __builtin_amdgcn_s_setprio(0);

    short8 nk[2], nv[2];
    if (more) {
      #pragma unroll
      for (int c=0;c<2;++c){
        const int e = t + c*256; const int row = e>>3, sl = e&7;
        nk[c] = *(const short8*)(Kh + (size_t)(b*4096 + (kt+1)*64 + row)*1024 + h*64 + sl*8);
        nv[c] = *(const short8*)(Vt + (size_t)(bh*64 + row)*4096 + (kt+1)*64 + sl*8);
      }
    }

    #pragma unroll
    for (int qh=0; qh<2; ++qh) {
      f32x4 lp = {0.f,0.f,0.f,0.f};
      #pragma unroll
      for (int kh=0;kh<2;++kh)
        #pragma unroll
        for (int r=0;r<16;++r) {
          const float p = exp2a(sA[qh][kh][r]);
          sA[qh][kh][r] = p;
          lp[r&3] += p;
        }
      l_run[qh] += (lp[0]+lp[1]) + (lp[2]+lp[3]);
    }

    __builtin_amdgcn_s_setprio(1);
    #pragma unroll
    for (int tt=0;tt<4;++tt) {
      const int kh = tt>>1, ro = (tt&1)*8;
      unsigned w0[4], w1[4];
      {
        unsigned c01 = cvtpk(sA[0][kh][ro+0], sA[0][kh][ro+1]);
        unsigned c23 = cvtpk(sA[0][kh][ro+2], sA[0][kh][ro+3]);
        unsigned c45 = cvtpk(sA[0][kh][ro+4], sA[0][kh][ro+5]);
        unsigned c67 = cvtpk(sA[0][kh][ro+6], sA[0][kh][ro+7]);
        uint2v r02 = plswap(c01, c45);
        uint2v r13 = plswap(c23, c67);
        w0[0]=r02[0]; w0[1]=r13[0]; w0[2]=r02[1]; w0[3]=r13[1];
      }
      {
        unsigned c01 = cvtpk(sA[1][kh][ro+0], sA[1][kh][ro+1]);
        unsigned c23 = cvtpk(sA[1][kh][ro+2], sA[1][kh][ro+3]);
        unsigned c45 = cvtpk(sA[1][kh][ro+4], sA[1][kh][ro+5]);
        unsigned c67 = cvtpk(sA[1][kh][ro+6], sA[1][kh][ro+7]);
        uint2v r02 = plswap(c01, c45);
        uint2v r13 = plswap(c23, c67);
        w1[0]=r02[0]; w1[1]=r13[0]; w1[2]=r02[1]; w1[3]=r13[1];
      }
      #pragma unroll
      for (int n=0;n<2;++n) {
        short8 vf = *(const short8*)(VsC + (n*32+l31)*128 + ((tt*32 + hi*16) ^ rsw));
        uint4v wp0 = {w0[0], w0[1], w0[2], w0[3]};
        uint4v wp1 = {w1[0], w1[1], w1[2], w1[3]};
        oA[0][n] = __builtin_amdgcn_mfma_f32_32x32x16_bf16(vf, __builtin_bit_cast(short8, wp0), oA[0][n], 0,0,0);
        oA[1][n] = __builtin_amdgcn_mfma_f32_32x32x16_bf16(vf, __builtin_bit_cast(short8, wp1), oA[1][n], 0,0,0);
      }
    }
    __builtin_amdgcn_s_setprio(0);

    if (more) {
      #pragma unroll
      for (int c=0;c<2;++c){
        const int e = t + c*256; const int row = e>>3, sl = e&7;
        const int byte = row*128 + ((sl*16) ^ ((row&7)<<4));
        *(short8*)(KsBufB + (cur^1)*8192 + byte) = nk[c];
        *(short8*)(VsBufB + (cur^1)*8192 + byte) = nv[c];
      }
    }
    __syncthreads();
  }

  char* ot = smem + wv*4096;
  #pragma unroll
  for (int qh=0; qh<2; ++qh) {
    float lr = l_run[qh];
    {
      uint2v rl = plswap(__builtin_bit_cast(unsigned, lr), __builtin_bit_cast(unsigned, lr));
      lr += __builtin_bit_cast(float, lo ? rl[1] : rl[0]);
    }
    const float inv = 1.0f / lr;
    #pragma unroll
    for (int n=0;n<2;++n)
      #pragma unroll
      for (int rq=0;rq<4;++rq) {
        const unsigned w0 = cvtpk(oA[qh][n][rq*4+0]*inv, oA[qh][n][rq*4+1]*inv);
        const unsigned w1 = cvtpk(oA[qh][n][rq*4+2]*inv, oA[qh][n][rq*4+3]*inv);
        const int sl = n*4 + rq;
        const int byte = l31*128 + ((sl*16) ^ ((l31&7)<<4)) + hi*8;
        *(unsigned*)(ot + byte)     = w0;
        *(unsigned*)(ot + byte + 4) = w1;
      }
    asm volatile("s_waitcnt lgkmcnt(0)" ::: "memory");
    __builtin_amdgcn_sched_barrier(0);

    const int row = lane >> 1, half = lane & 1;
    const int orow = b*4096 + q0 + wv*64 + qh*32 + row;
    #pragma unroll
    for (int i=0;i<4;++i) {
      const int sl = half*4 + i;
      short8 vv = *(const short8*)(ot + row*128 + ((sl*16) ^ ((row&7)<<4)));
      *(short8*)(O + (size_t)orow*1024 + h*64 + half*32 + i*8) = vv;
    }
    asm volatile("s_waitcnt lgkmcnt(0)" ::: "memory");
    __builtin_amdgcn_sched_barrier(0);
  }
}

extern "C" void kernel_launch(void* const* d_in, const int* in_sizes, int n_in,
                              void* d_out, int out_size, void* d_ws, size_t ws_size,
                              hipStream_t stream)
{
  const float* q    = (const float*)d_in[0];
  const float* k    = (const float*)d_in[1];
  const float* v    = (const float*)d_in[2];
  const int*   mask = (const int*)d_in[3];
  const float* w_q  = (const float*)d_in[4];
  const float* b_q  = (const float*)d_in[5];
  const float* w_k  = (const float*)d_in[6];
  const float* b_k  = (const float*)d_in[7];
  const float* w_v  = (const float*)d_in[8];
  const float* b_v  = (const float*)d_in[9];
  const float* w_o  = (const float*)d_in[10];
  const float* b_o  = (const float*)d_in[11];
  float* out = (float*)d_out;

  char* ws = (char*)d_ws;
  const size_t SZ = (size_t)8192*1024*2;   // one bf16 [8192][1024] buffer = 16MB
  short* QH = (short*)(ws);
  short* KH = (short*)(ws + SZ);
  short* OB = (short*)(ws + 2*SZ);         // V-proj output, then reused for attn out
  short* VT = (short*)(ws + 3*SZ);
  short* KC = (short*)(ws + 4*SZ);         // compacted K (ws >= 96MB proven in R16)
  int*   CNT = (int*)(ws + 5*SZ);          // 8B
  short* VH = OB;

  const float QSCALE = 0.125f * 1.44269504f;

  QKVArgs qa;
  qa.aq = q;   qa.ak = k;   qa.av = v;
  qa.wq = w_q; qa.wk = w_k; qa.wv = w_v;
  qa.bq = b_q; qa.bk = b_k; qa.bv = b_v;
  qa.cq = QH;  qa.ck = KH;  qa.cv = VH;
  qa.sq = QSCALE; qa.sk = 1.0f; qa.sv = 1.0f;

  dim3 bG(256);
  hipLaunchKernelGGL(qkv_gemm_kernel, dim3(64, 8, 3), bG, 0, stream, qa, 8192, 1024, 1024);
  hipLaunchKernelGGL(prep_kernel, dim3(2560), bG, 0, stream, mask, KH, VH, KC, VT, CNT);
  hipLaunchKernelGGL(flash_kernel, dim3(16, 32), bG, 0, stream, QH, KC, VT, CNT, OB);
  hipLaunchKernelGGL((gemm_bt_kernel<short, float>), dim3(64, 8), bG, 0, stream, OB, w_o, b_o, out, 8192, 1024, 1024, 1.0f);
}